// Round 4
// baseline (508.375 us; speedup 1.0000x reference)
//
#include <hip/hip_runtime.h>
#include <math.h>

#define T_LEN 2048
#define B_SZ 2
#define EMB 1024
#define HEADS 16
#define HD 64
#define BH (B_SZ*HEADS)       // 32
#define R_ROWS (T_LEN*B_SZ)   // 4096

typedef unsigned short u16;
typedef __attribute__((ext_vector_type(8))) short bf16x8;
typedef __attribute__((ext_vector_type(4))) short bf16x4;
typedef __attribute__((ext_vector_type(4))) float f32x4;

#define MFMA32(a,b,c) __builtin_amdgcn_mfma_f32_16x16x32_bf16(a,b,c,0,0,0)
#if __has_builtin(__builtin_amdgcn_mfma_f32_16x16x16_bf16)
#define MFMA16(a,b,c) __builtin_amdgcn_mfma_f32_16x16x16_bf16(a,b,c,0,0,0)
#else
#define MFMA16(a,b,c) __builtin_amdgcn_mfma_f32_16x16x16bf16_1k(a,b,c,0,0,0)
#endif

__device__ __forceinline__ u16 f2bf(float f) {
    union { float f; unsigned int u; } v; v.f = f;
    unsigned int r = v.u + 0x7fffu + ((v.u >> 16) & 1u);
    return (u16)(r >> 16);
}
__device__ __forceinline__ float bf2f(u16 h) {
    union { unsigned int u; float f; } v; v.u = ((unsigned int)h) << 16;
    return v.f;
}
__device__ __forceinline__ ushort4 hi4(float4 x) {
    ushort4 u; u.x = f2bf(x.x); u.y = f2bf(x.y); u.z = f2bf(x.z); u.w = f2bf(x.w); return u;
}
__device__ __forceinline__ ushort4 lo4(float4 x, ushort4 h) {
    ushort4 u;
    u.x = f2bf(x.x - bf2f(h.x));
    u.y = f2bf(x.y - bf2f(h.y));
    u.z = f2bf(x.z - bf2f(h.z));
    u.w = f2bf(x.w - bf2f(h.w));
    return u;
}
// pack two fp32 -> packed bf16 pair (round-half-up) via v_perm: 3 instrs / 2 vals
__device__ __forceinline__ unsigned pk2bf(float a, float b) {
    union { float f; unsigned u; } x, y; x.f = a; y.f = b;
    return __builtin_amdgcn_perm(y.u + 0x8000u, x.u + 0x8000u, 0x07060302u);
}
// async global->LDS, 16B/lane; lds base wave-uniform (lane lands at base + lane*16)
__device__ __forceinline__ void lds_cp16(u16* lds, const u16* g) {
    __builtin_amdgcn_global_load_lds(
        (const __attribute__((address_space(1))) unsigned int*)(const void*)g,
        (__attribute__((address_space(3))) unsigned int*)(void*)lds,
        16, 0, 0);
}

// ---------------- fp32 -> bf16 hi/lo split ----------------------------------
__global__ __launch_bounds__(256)
void conv_kernel(const float* __restrict__ src, u16* __restrict__ hi, u16* __restrict__ lo)
{
    size_t base = ((size_t)blockIdx.x*256 + threadIdx.x)*8;
    float4 a = *(const float4*)(src + base);
    float4 b = *(const float4*)(src + base + 4);
    ushort4 h0 = hi4(a), h1 = hi4(b);
    ushort4 l0 = lo4(a, h0), l1 = lo4(b, h1);
    *(ushort4*)(hi + base)     = h0;
    *(ushort4*)(hi + base + 4) = h1;
    *(ushort4*)(lo + base)     = l0;
    *(ushort4*)(lo + base + 4) = l1;
}
// 4 weight splits in one launch (blockIdx.y picks tensor)
__global__ __launch_bounds__(256)
void conv4_kernel(const float* s0, const float* s1, const float* s2, const float* s3,
                  u16* h0, u16* h1, u16* h2, u16* h3,
                  u16* l0, u16* l1, u16* l2, u16* l3)
{
    const float* s; u16 *h, *l;
    switch (blockIdx.y) {
        case 0: s=s0; h=h0; l=l0; break;
        case 1: s=s1; h=h1; l=l1; break;
        case 2: s=s2; h=h2; l=l2; break;
        default: s=s3; h=h3; l=l3; break;
    }
    size_t base = ((size_t)blockIdx.x*256 + threadIdx.x)*8;
    float4 a = *(const float4*)(s + base);
    float4 b = *(const float4*)(s + base + 4);
    ushort4 hh0 = hi4(a), hh1 = hi4(b);
    ushort4 ll0 = lo4(a, hh0), ll1 = lo4(b, hh1);
    *(ushort4*)(h + base)     = hh0;
    *(ushort4*)(h + base + 4) = hh1;
    *(ushort4*)(l + base)     = ll0;
    *(ushort4*)(l + base + 4) = ll1;
}

// ---------------- MFMA projection GEMM (compensated bf16, dbuf pipeline) -----
// C = A·B^T + bias. 128(M)x64(N), BK=32, single barrier/iter, LDS double buffer:
// barrier -> issue cp16(k+1 -> other buf) -> ds_read+MFMA(current buf).
__global__ __launch_bounds__(256)
void proj_mfma(const u16* __restrict__ Ahi, const u16* __restrict__ Alo,
               const u16* __restrict__ Bhi, const u16* __restrict__ Blo,
               const float* __restrict__ bias,
               float* __restrict__ outF, u16* __restrict__ outHi, u16* __restrict__ outLo,
               float scale, int mode)
{
    __shared__ __align__(16) u16 sAh[2][128*32];
    __shared__ __align__(16) u16 sAl[2][128*32];
    __shared__ __align__(16) u16 sBh[2][64*32];
    __shared__ __align__(16) u16 sBl[2][64*32];
    const int tid = threadIdx.x;
    const int w = tid >> 6, ln = tid & 63, lm = ln & 15, lq = ln >> 4;
    const int wm = w & 1, wn = w >> 1;
    const int m0 = blockIdx.x * 128, n0 = blockIdx.y * 64;
    const int K = 1024;
    const int ar = ln >> 2;      // staging row within 16-row chunk
    const int ac = ln & 3;       // staging 16B chunk within 64B row

    f32x4 acc[4][2];
#pragma unroll
    for (int i = 0; i < 4; ++i)
#pragma unroll
        for (int j = 0; j < 2; ++j) acc[i][j] = (f32x4){0.f,0.f,0.f,0.f};

    // prologue: stage k0=0 into buf0
    {
#pragma unroll
        for (int i = 0; i < 2; ++i) {
            int ch = w*2 + i;
            int r = ch*16 + ar;
            int c = ac ^ ((r >> 1) & 3);
            size_t g = (size_t)(m0 + r)*K + c*8;
            lds_cp16(&sAh[0][ch*512], Ahi + g);
            lds_cp16(&sAl[0][ch*512], Alo + g);
        }
        int r = w*16 + ar;
        int c = ac ^ ((r >> 1) & 3);
        size_t g = (size_t)(n0 + r)*K + c*8;
        lds_cp16(&sBh[0][w*512], Bhi + g);
        lds_cp16(&sBl[0][w*512], Blo + g);
    }

    for (int k0 = 0; k0 < 1024; k0 += 32) {
        const int cur = (k0 >> 5) & 1;
        __syncthreads();          // buf[cur] staged; buf[cur^1] reads done (lgkm drained)
        if (k0 + 32 < 1024) {
            const int nxt = cur ^ 1;
#pragma unroll
            for (int i = 0; i < 2; ++i) {
                int ch = w*2 + i;
                int r = ch*16 + ar;
                int c = ac ^ ((r >> 1) & 3);
                size_t g = (size_t)(m0 + r)*K + k0 + 32 + c*8;
                lds_cp16(&sAh[nxt][ch*512], Ahi + g);
                lds_cp16(&sAl[nxt][ch*512], Alo + g);
            }
            int r = w*16 + ar;
            int c = ac ^ ((r >> 1) & 3);
            size_t g = (size_t)(n0 + r)*K + k0 + 32 + c*8;
            lds_cp16(&sBh[nxt][w*512], Bhi + g);
            lds_cp16(&sBl[nxt][w*512], Blo + g);
        }
        bf16x8 afh[4], afl[4], bfh[2], bfl[2];
#pragma unroll
        for (int i = 0; i < 4; ++i) {
            int row = wm*64 + i*16 + lm;
            int off = row*32 + (lq ^ ((row >> 1) & 3))*8;
            afh[i] = *(const bf16x8*)&sAh[cur][off];
            afl[i] = *(const bf16x8*)&sAl[cur][off];
        }
#pragma unroll
        for (int j = 0; j < 2; ++j) {
            int row = wn*32 + j*16 + lm;
            int off = row*32 + (lq ^ ((row >> 1) & 3))*8;
            bfh[j] = *(const bf16x8*)&sBh[cur][off];
            bfl[j] = *(const bf16x8*)&sBl[cur][off];
        }
#pragma unroll
        for (int i = 0; i < 4; ++i)
#pragma unroll
            for (int j = 0; j < 2; ++j) {
                f32x4 a = acc[i][j];
                a = MFMA32(afh[i], bfl[j], a);
                a = MFMA32(afl[i], bfh[j], a);
                a = MFMA32(afh[i], bfh[j], a);
                acc[i][j] = a;
            }
    }

    if (mode == 0) {
#pragma unroll
        for (int j = 0; j < 2; ++j) {
            float bv = bias[n0 + wn*32 + j*16 + lm];
#pragma unroll
            for (int i = 0; i < 4; ++i)
#pragma unroll
                for (int r = 0; r < 4; ++r) {
                    int gm = m0 + wm*64 + i*16 + lq*4 + r;
                    outF[(size_t)gm*EMB + n0 + wn*32 + j*16 + lm] = acc[i][j][r] + bv;
                }
        }
    } else if (mode == 1) {
        const int h = n0 >> 6;
#pragma unroll
        for (int j = 0; j < 2; ++j) {
            float bv = bias[n0 + wn*32 + j*16 + lm];
            int d = wn*32 + j*16 + lm;
#pragma unroll
            for (int i = 0; i < 4; ++i)
#pragma unroll
                for (int r = 0; r < 4; ++r) {
                    int gm = m0 + wm*64 + i*16 + lq*4 + r;
                    int t = gm >> 1, bb = gm & 1;
                    float val = (acc[i][j][r] + bv) * scale;
                    u16 hv = f2bf(val);
                    u16 lv = f2bf(val - bf2f(hv));
                    size_t o = ((size_t)(bb*HEADS + h)*T_LEN + t)*HD + d;
                    outHi[o] = hv; outLo[o] = lv;
                }
        }
    } else {  // mode 2: A=W rows (out channel), B=X rows (token) -> vT [bh][d][t]
#pragma unroll
        for (int i = 0; i < 4; ++i)
#pragma unroll
            for (int r = 0; r < 4; ++r) {
                int gm = m0 + wm*64 + i*16 + lq*4 + r;
                int h = gm >> 6, d = gm & 63;
                float bv = bias[gm];
#pragma unroll
                for (int j = 0; j < 2; ++j) {
                    int gn = n0 + wn*32 + j*16 + lm;
                    int t = gn >> 1, bb = gn & 1;
                    outHi[((size_t)(bb*HEADS + h)*HD + d)*T_LEN + t] = f2bf(acc[i][j][r] + bv);
                }
            }
    }
}

// ---------------- MFMA flash attention (dbuf pipeline, base-2 softmax) -------
// Q pre-scaled by 0.125*log2(e); m,l tracked base-2. XCD swizzle: all 16
// t-tiles of a bh land on one XCD (bh resident in its L2).
__global__ __launch_bounds__(256)
void flash_kernel(const u16* __restrict__ qHi, const u16* __restrict__ qLo,
                  const u16* __restrict__ kHi, const u16* __restrict__ kLo,
                  const u16* __restrict__ vT,
                  u16* __restrict__ attnHi, u16* __restrict__ attnLo,
                  float* __restrict__ mbuf, float* __restrict__ lbuf)
{
    __shared__ __align__(16) u16 Khi[2][64*64];
    __shared__ __align__(16) u16 Klo[2][64*64];
    __shared__ __align__(16) u16 Vts[2][64*64];   // logical [d][s]
    const int tid = threadIdx.x;
    const int w = tid >> 6, ln = tid & 63, lm = ln & 15, lq = ln >> 4;
    const int bid = blockIdx.x;                   // 512 blocks, 1-D
    const int xcd = bid & 7, idx = bid >> 3;
    const int bh = xcd + 8*(idx & 3);
    const int t0 = (idx >> 2) << 7;
    const int b = bh >> 4, hh = bh & 15;
    const int sr = ln >> 3, scc = ln & 7;         // staging decode (128B rows)
    const u16* kgH = kHi + (size_t)bh*T_LEN*HD;
    const u16* kgL = kLo + (size_t)bh*T_LEN*HD;
    const u16* vg  = vT  + (size_t)bh*HD*T_LEN;

    // prologue: stage s0=0 into buf0
#pragma unroll
    for (int i = 0; i < 2; ++i) {
        int ch = w*2 + i;
        int r = ch*8 + sr;
        int c = scc ^ (r & 7);
        lds_cp16(&Khi[0][ch*512], kgH + (size_t)r*HD + c*8);
        lds_cp16(&Klo[0][ch*512], kgL + (size_t)r*HD + c*8);
        lds_cp16(&Vts[0][ch*512], vg + (size_t)r*T_LEN + c*8);
    }

    bf16x8 qfhi[2][2], qflo[2][2];
#pragma unroll
    for (int nt = 0; nt < 2; ++nt) {
        size_t qo = ((size_t)bh*T_LEN + t0 + w*32 + nt*16 + lm)*HD;
#pragma unroll
        for (int f = 0; f < 2; ++f) {
            qfhi[nt][f] = *(const bf16x8*)(qHi + qo + f*32 + lq*8);
            qflo[nt][f] = *(const bf16x8*)(qLo + qo + f*32 + lq*8);
        }
    }

    f32x4 O[2][4];
    float m_t[2], l_t[2];
#pragma unroll
    for (int nt = 0; nt < 2; ++nt) {
        m_t[nt] = -INFINITY; l_t[nt] = 0.f;
#pragma unroll
        for (int dt = 0; dt < 4; ++dt) O[nt][dt] = (f32x4){0.f,0.f,0.f,0.f};
    }

    for (int s0 = 0; s0 < T_LEN; s0 += 64) {
        const int cur = (s0 >> 6) & 1;
        __syncthreads();
        if (s0 + 64 < T_LEN) {
            const int nxt = cur ^ 1;
#pragma unroll
            for (int i = 0; i < 2; ++i) {
                int ch = w*2 + i;
                int r = ch*8 + sr;
                int c = scc ^ (r & 7);
                lds_cp16(&Khi[nxt][ch*512], kgH + (size_t)(s0 + 64 + r)*HD + c*8);
                lds_cp16(&Klo[nxt][ch*512], kgL + (size_t)(s0 + 64 + r)*HD + c*8);
                lds_cp16(&Vts[nxt][ch*512], vg + (size_t)r*T_LEN + s0 + 64 + c*8);
            }
        }

        f32x4 S[2][4];
#pragma unroll
        for (int ms = 0; ms < 4; ++ms) {
            const int kr = ms*16 + lm;
            const int sw = kr & 7;
            const u16* rowH = &Khi[cur][kr*64];
            const u16* rowL = &Klo[cur][kr*64];
            bf16x8 ah0 = *(const bf16x8*)(rowH + ((lq    ) ^ sw)*8);
            bf16x8 ah1 = *(const bf16x8*)(rowH + ((lq + 4) ^ sw)*8);
            bf16x8 al0 = *(const bf16x8*)(rowL + ((lq    ) ^ sw)*8);
            bf16x8 al1 = *(const bf16x8*)(rowL + ((lq + 4) ^ sw)*8);
#pragma unroll
            for (int nt = 0; nt < 2; ++nt) {
                f32x4 s4 = {0.f,0.f,0.f,0.f};
                s4 = MFMA32(al0, qfhi[nt][0], s4);
                s4 = MFMA32(al1, qfhi[nt][1], s4);
                s4 = MFMA32(ah0, qflo[nt][0], s4);
                s4 = MFMA32(ah1, qflo[nt][1], s4);
                s4 = MFMA32(ah0, qfhi[nt][0], s4);
                s4 = MFMA32(ah1, qfhi[nt][1], s4);
                S[nt][ms] = s4;
            }
        }

        bf16x4 P[2][4];
        float alpha[2];
#pragma unroll
        for (int nt = 0; nt < 2; ++nt) {
            float mx = -INFINITY;
#pragma unroll
            for (int ms = 0; ms < 4; ++ms)
#pragma unroll
                for (int r = 0; r < 4; ++r) mx = fmaxf(mx, S[nt][ms][r]);
            mx = fmaxf(mx, __shfl_xor(mx, 16));
            mx = fmaxf(mx, __shfl_xor(mx, 32));
            float mn = fmaxf(m_t[nt], mx);
            alpha[nt] = exp2f(m_t[nt] - mn);
            m_t[nt] = mn;
            float rs = 0.f;
#pragma unroll
            for (int ms = 0; ms < 4; ++ms) {
                float p0 = exp2f(S[nt][ms][0]-mn);
                float p1 = exp2f(S[nt][ms][1]-mn);
                float p2 = exp2f(S[nt][ms][2]-mn);
                float p3 = exp2f(S[nt][ms][3]-mn);
                rs += (p0+p1)+(p2+p3);
                union { unsigned u[2]; bf16x4 v; } pu;
                pu.u[0] = pk2bf(p0, p1);
                pu.u[1] = pk2bf(p2, p3);
                P[nt][ms] = pu.v;
            }
            rs += __shfl_xor(rs, 16);
            rs += __shfl_xor(rs, 32);
            l_t[nt] = l_t[nt]*alpha[nt] + rs;
        }
#pragma unroll
        for (int nt = 0; nt < 2; ++nt) {
            f32x4 av;
#pragma unroll
            for (int r = 0; r < 4; ++r) av[r] = __shfl(alpha[nt], lq*4 + r);
#pragma unroll
            for (int dt = 0; dt < 4; ++dt) O[nt][dt] *= av;
        }
#pragma unroll
        for (int dt = 0; dt < 4; ++dt) {
            const int d = dt*16 + lm;
            const int dw = d & 7;
#pragma unroll
            for (int ms = 0; ms < 4; ++ms) {
                bf16x4 vf = *(const bf16x4*)&Vts[cur][d*64 + ((2*ms + (lq>>1)) ^ dw)*8 + (lq&1)*4];
#pragma unroll
                for (int nt = 0; nt < 2; ++nt)
                    O[nt][dt] = MFMA16(P[nt][ms], vf, O[nt][dt]);
            }
        }
    }

#pragma unroll
    for (int nt = 0; nt < 2; ++nt) {
        float inv = 1.0f / l_t[nt];
        f32x4 iv;
#pragma unroll
        for (int r = 0; r < 4; ++r) iv[r] = __shfl(inv, lq*4 + r);
        int tbase = t0 + w*32 + nt*16;
        if (lq == 0) {
            mbuf[(size_t)bh*T_LEN + tbase + lm] = m_t[nt];   // base-2 max
            lbuf[(size_t)bh*T_LEN + tbase + lm] = l_t[nt];
        }
#pragma unroll
        for (int dt = 0; dt < 4; ++dt)
#pragma unroll
            for (int r = 0; r < 4; ++r) {
                int t = tbase + lq*4 + r;
                float val = O[nt][dt][r] * iv[r];
                u16 hv = f2bf(val);
                u16 lv = f2bf(val - bf2f(hv));
                size_t o = ((size_t)t*B_SZ + b)*EMB + hh*HD + dt*16 + lm;
                attnHi[o] = hv; attnLo[o] = lv;
            }
    }
}

// ---------------- avg weights: MFMA recompute S^T, dbuf K + q-reg prefetch ---
__global__ __launch_bounds__(256)
void avg_kernel(const u16* __restrict__ qHi, const u16* __restrict__ qLo,
                const u16* __restrict__ kHi, const u16* __restrict__ kLo,
                const float* __restrict__ mbuf, const float* __restrict__ lbuf,
                float* __restrict__ avg)
{
    __shared__ __align__(16) u16 Khi[2][128*64];
    __shared__ __align__(16) u16 Klo[2][128*64];
    const int tid = threadIdx.x;
    const int w = tid >> 6, ln = tid & 63, lm = ln & 15, lq = ln >> 4;
    const int bid = blockIdx.x;                    // 512 blocks, 1-D
    const int xcd = bid & 7, idx = bid >> 3;
    const int combo = xcd + 8*(idx & 3);           // 0..31 -> (b, s0)
    const int s0 = (combo & 15) << 7;
    const int b  = combo >> 4;
    const int t0 = (idx >> 2) << 7;
    const int sr = ln >> 3, scc = ln & 7;

    f32x4 acc[2][8];
#pragma unroll
    for (int nt = 0; nt < 2; ++nt)
#pragma unroll
        for (int ms = 0; ms < 8; ++ms) acc[nt][ms] = (f32x4){0.f,0.f,0.f,0.f};

    // prologue: stage K(h=0) into buf0; preload q(0) regs
#pragma unroll
    for (int i = 0; i < 4; ++i) {
        int ch = w*4 + i;
        int r = ch*8 + sr;
        int c = scc ^ (r & 7);
        size_t g = ((size_t)(b*HEADS)*T_LEN + s0 + r)*HD + c*8;
        lds_cp16(&Khi[0][ch*512], kHi + g);
        lds_cp16(&Klo[0][ch*512], kLo + g);
    }
    bf16x8 qh_c[2][2], ql_c[2][2];
    float mv_c[2], lv_c[2];
#pragma unroll
    for (int nt = 0; nt < 2; ++nt) {
        int t = t0 + w*32 + nt*16 + lm;
        size_t qo = ((size_t)(b*HEADS)*T_LEN + t)*HD;
#pragma unroll
        for (int f = 0; f < 2; ++f) {
            qh_c[nt][f] = *(const bf16x8*)(qHi + qo + f*32 + lq*8);
            ql_c[nt][f] = *(const bf16x8*)(qLo + qo + f*32 + lq*8);
        }
        mv_c[nt] = mbuf[(size_t)(b*HEADS)*T_LEN + t];
        lv_c[nt] = 1.0f / lbuf[(size_t)(b*HEADS)*T_LEN + t];
    }

    for (int h = 0; h < HEADS; ++h) {
        const int cur = h & 1;
        __syncthreads();
        bf16x8 qh_n[2][2], ql_n[2][2];
        float mv_n[2] = {0.f,0.f}, lv_n[2] = {0.f,0.f};
        if (h + 1 < HEADS) {
            const int nxt = cur ^ 1;
            const int bh1 = b*HEADS + h + 1;
#pragma unroll
            for (int i = 0; i < 4; ++i) {
                int ch = w*4 + i;
                int r = ch*8 + sr;
                int c = scc ^ (r & 7);
                size_t g = ((size_t)bh1*T_LEN + s0 + r)*HD + c*8;
                lds_cp16(&Khi[nxt][ch*512], kHi + g);
                lds_cp16(&Klo[nxt][ch*512], kLo + g);
            }
#pragma unroll
            for (int nt = 0; nt < 2; ++nt) {
                int t = t0 + w*32 + nt*16 + lm;
                size_t qo = ((size_t)bh1*T_LEN + t)*HD;
#pragma unroll
                for (int f = 0; f < 2; ++f) {
                    qh_n[nt][f] = *(const bf16x8*)(qHi + qo + f*32 + lq*8);
                    ql_n[nt][f] = *(const bf16x8*)(qLo + qo + f*32 + lq*8);
                }
                mv_n[nt] = mbuf[(size_t)bh1*T_LEN + t];
                lv_n[nt] = 1.0f / lbuf[(size_t)bh1*T_LEN + t];
            }
        }
#pragma unroll
        for (int ms = 0; ms < 8; ++ms) {
            const int kr = ms*16 + lm;
            const int sw = kr & 7;
            const u16* rowH = &Khi[cur][kr*64];
            const u16* rowL = &Klo[cur][kr*64];
            bf16x8 ah0 = *(const bf16x8*)(rowH + ((lq    ) ^ sw)*8);
            bf16x8 ah1 = *(const bf16x8*)(rowH + ((lq + 4) ^ sw)*8);
            bf16x8 al0 = *(const bf16x8*)(rowL + ((lq    ) ^ sw)*8);
            bf16x8 al1 = *(const bf16x8*)(rowL + ((lq + 4) ^ sw)*8);
#pragma unroll
            for (int nt = 0; nt < 2; ++nt) {
                f32x4 s4 = {0.f,0.f,0.f,0.f};
                s4 = MFMA32(al0, qh_c[nt][0], s4);
                s4 = MFMA32(al1, qh_c[nt][1], s4);
                s4 = MFMA32(ah0, ql_c[nt][0], s4);
                s4 = MFMA32(ah1, ql_c[nt][1], s4);
                s4 = MFMA32(ah0, qh_c[nt][0], s4);
                s4 = MFMA32(ah1, qh_c[nt][1], s4);
                f32x4 a = acc[nt][ms];
                a[0] += exp2f(s4[0]-mv_c[nt])*lv_c[nt];
                a[1] += exp2f(s4[1]-mv_c[nt])*lv_c[nt];
                a[2] += exp2f(s4[2]-mv_c[nt])*lv_c[nt];
                a[3] += exp2f(s4[3]-mv_c[nt])*lv_c[nt];
                acc[nt][ms] = a;
            }
        }
        if (h + 1 < HEADS) {
#pragma unroll
            for (int nt = 0; nt < 2; ++nt) {
#pragma unroll
                for (int f = 0; f < 2; ++f) { qh_c[nt][f] = qh_n[nt][f]; ql_c[nt][f] = ql_n[nt][f]; }
                mv_c[nt] = mv_n[nt]; lv_c[nt] = lv_n[nt];
            }
        }
    }
    const float sc = 1.0f / HEADS;
#pragma unroll
    for (int nt = 0; nt < 2; ++nt) {
        int t = t0 + w*32 + nt*16 + lm;
#pragma unroll
        for (int ms = 0; ms < 8; ++ms) {
            float4 v;
            v.x = acc[nt][ms][0]*sc; v.y = acc[nt][ms][1]*sc;
            v.z = acc[nt][ms][2]*sc; v.w = acc[nt][ms][3]*sc;
            *(float4*)(avg + ((size_t)b*T_LEN + t)*T_LEN + s0 + ms*16 + lq*4) = v;
        }
    }
}

extern "C" void kernel_launch(void* const* d_in, const int* in_sizes, int n_in,
                              void* d_out, int out_size, void* d_ws, size_t ws_size,
                              hipStream_t stream)
{
    const float* query = (const float*)d_in[0];
    const float* key   = (const float*)d_in[1];
    const float* value = (const float*)d_in[2];
    const float* Wq = (const float*)d_in[3];
    const float* bq = (const float*)d_in[4];
    const float* Wk = (const float*)d_in[5];
    const float* bk = (const float*)d_in[6];
    const float* Wv = (const float*)d_in[7];
    const float* bv = (const float*)d_in[8];
    const float* Wo = (const float*)d_in[9];
    const float* bo = (const float*)d_in[10];

    float* out = (float*)d_out;                  // [T,B,E]
    float* avg = out + (size_t)R_ROWS*EMB;       // [B,T,S]

    const size_t NX = (size_t)R_ROWS*EMB;        // 4194304
    const size_t NW = (size_t)EMB*EMB;           // 1048576
    u16* wsu = (u16*)d_ws;
    u16* cHi  = wsu;            u16* cLo  = cHi + NX;     // conv scratch; later attnHi/Lo
    u16* WqHi = cLo + NX;       u16* WqLo = WqHi + NW;
    u16* WkHi = WqLo + NW;      u16* WkLo = WkHi + NW;
    u16* WvHi = WkLo + NW;      u16* WvLo = WvHi + NW;
    u16* WoHi = WvLo + NW;      u16* WoLo = WoHi + NW;
    u16* qHi  = WoLo + NW;      u16* qLo  = qHi + NX;     // head-major [bh][t][d]
    u16* kHi  = qLo + NX;       u16* kLo  = kHi + NX;
    u16* vT   = kLo + NX;                                  // [bh][d][t]
    float* mb = (float*)(vT + NX);
    float* lb = mb + (size_t)BH*T_LEN;

    const float scale_q = 0.125f * 1.4426950408889634f;   // hd^-0.5 * log2(e)

    conv4_kernel<<<dim3(NW/2048, 4), 256, 0, stream>>>(Wq, Wk, Wv, Wo,
                                                       WqHi, WkHi, WvHi, WoHi,
                                                       WqLo, WkLo, WvLo, WoLo);

    dim3 gP(R_ROWS/128, EMB/64);       // (32,16) modes 0/1
    dim3 gPv(EMB/128, R_ROWS/64);      // (8,64)  mode 2

    conv_kernel<<<NX/2048, 256, 0, stream>>>(query, cHi, cLo);
    proj_mfma<<<gP, 256, 0, stream>>>(cHi, cLo, WqHi, WqLo, bq, nullptr, qHi, qLo, scale_q, 1);
    conv_kernel<<<NX/2048, 256, 0, stream>>>(key, cHi, cLo);
    proj_mfma<<<gP, 256, 0, stream>>>(cHi, cLo, WkHi, WkLo, bk, nullptr, kHi, kLo, 1.0f, 1);
    conv_kernel<<<NX/2048, 256, 0, stream>>>(value, cHi, cLo);
    proj_mfma<<<gPv, 256, 0, stream>>>(WvHi, WvLo, cHi, cLo, bv, nullptr, vT, nullptr, 1.0f, 2);

    flash_kernel<<<512, 256, 0, stream>>>(qHi, qLo, kHi, kLo, vT, cHi, cLo, mb, lb);
    proj_mfma<<<gP, 256, 0, stream>>>(cHi, cLo, WoHi, WoLo, bo, out, nullptr, nullptr, 1.0f, 0);
    avg_kernel<<<512, 256, 0, stream>>>(qHi, qLo, kHi, kLo, mb, lb, avg);
}